// Round 2
// baseline (574.662 us; speedup 1.0000x reference)
//
#include <hip/hip_runtime.h>
#include <math.h>

typedef unsigned int uint32;
typedef unsigned short u16;

// ---------------- workspace layout (float indices) ----------------
#define OFF_STATS 0        // 48: sum,sumsq per (t=q/k/v, b, g)
#define OFF_MUSR  64       // 48: mu, rsigma
#define OFF_L     128      // 512: softmax denominators per (b,c)
#define OFF_MROW  640      // 512: softmax row max (of nk)
#define OFF_MAXV  1280     // 512: raw-k row max
#define OFF_MINV  1792     // 512: raw-k row min
#define OFF_CTX   2048     // 32768: raw context [b,h][d][e]
#define OFF_MBT   34816    // 2*65536: MbT[b][c'][co]  (M_b + I, transposed)
#define OFF_KB    165888   // 512: K_b
#define OFF_Z     167936   // z as bf16: 16777216 u16 = 8388608 float slots
#define OFF_DG    8556544  // 196608: dg conv output (pre-bias)
#define OFF_CTXP  8753152  // 64*8*4096 ctx partials (part mode)
#define OFF_LP    10850304 // 64*8*64 L partials
#define OFF_DGP   8753152  // 32*196608 dg partials (aliases CTXP/LP, consumed earlier)
#define WS_PART_FLOATS 15044608

__device__ __forceinline__ float bf2f(u16 h){ return __uint_as_float(((uint32)h)<<16); }
__device__ __forceinline__ u16 f2bf(float f){ uint32 u=__float_as_uint(f); return (u16)((u + 0x7fffu + ((u>>16)&1u))>>16); }

// ---------------- 1. stats: sum/sumsq per group + per-row min/max of k ----------------
__global__ __launch_bounds__(256) void k_stats(const float* __restrict__ q, const float* __restrict__ k,
                                               const float* __restrict__ v, float* __restrict__ ws){
  int gid = blockIdx.x >> 6;     // 0..23 = t*8 + bg
  int chunk = blockIdx.x & 63;   // row within group
  int t = gid >> 3; int bg = gid & 7;
  const float* src = (t==0)? q : ((t==1)? k : v);
  const float* base = src + (size_t)bg*2097152 + (size_t)chunk*32768;
  int tid = threadIdx.x;
  float s=0.f, ss=0.f, mx=-INFINITY, mn=INFINITY;
  #pragma unroll 4
  for (int it=0; it<32; ++it){
    float4 x = *(const float4*)(base + it*1024 + tid*4);
    s += (x.x+x.y)+(x.z+x.w);
    ss = fmaf(x.x,x.x, fmaf(x.y,x.y, fmaf(x.z,x.z, fmaf(x.w,x.w, ss))));
    mx = fmaxf(mx, fmaxf(fmaxf(x.x,x.y), fmaxf(x.z,x.w)));
    mn = fminf(mn, fminf(fminf(x.x,x.y), fminf(x.z,x.w)));
  }
  for (int o=32;o>0;o>>=1){
    s  += __shfl_down(s,o);  ss += __shfl_down(ss,o);
    mx = fmaxf(mx, __shfl_down(mx,o)); mn = fminf(mn, __shfl_down(mn,o));
  }
  __shared__ float rsum[4], rssq[4], rmx[4], rmn[4];
  int lane = tid&63, w = tid>>6;
  if (lane==0){ rsum[w]=s; rssq[w]=ss; rmx[w]=mx; rmn[w]=mn; }
  __syncthreads();
  if (tid==0){
    atomicAdd(&ws[OFF_STATS + gid*2],   (rsum[0]+rsum[1])+(rsum[2]+rsum[3]));
    atomicAdd(&ws[OFF_STATS + gid*2+1], (rssq[0]+rssq[1])+(rssq[2]+rssq[3]));
    if (t==1){
      int r = bg*64 + chunk;  // one block per row -> plain store
      ws[OFF_MAXV + r] = fmaxf(fmaxf(rmx[0],rmx[1]),fmaxf(rmx[2],rmx[3]));
      ws[OFF_MINV + r] = fminf(fminf(rmn[0],rmn[1]),fminf(rmn[2],rmn[3]));
    }
  }
}

// ---------------- 2. finalize: mu/rsigma + softmax row max ----------------
__global__ void k_finalize(const float* __restrict__ gw, const float* __restrict__ gb, float* __restrict__ ws){
  int tid = threadIdx.x;
  if (tid < 24){
    float s=ws[OFF_STATS+2*tid], ss=ws[OFF_STATS+2*tid+1];
    const float inv = 1.f/2097152.f;
    float mu = s*inv;
    float var = ss*inv - mu*mu;
    ws[OFF_MUSR+2*tid]=mu; ws[OFF_MUSR+2*tid+1]=rsqrtf(var+1e-5f);
  }
  __syncthreads();
  if (tid < 512){
    int b=tid>>8, c=tid&255, g=c>>6;
    int gi = 8 + b*4 + g;                       // k-tensor stats
    float mu=ws[OFF_MUSR+2*gi], rs=ws[OFF_MUSR+2*gi+1];
    float a = rs*gw[c]; float beta = gb[c] - mu*a;
    float mx = ws[OFF_MAXV+tid], mn = ws[OFF_MINV+tid];
    ws[OFF_MROW+tid] = (a>=0.f)? fmaf(a,mx,beta) : fmaf(a,mn,beta); // exact max of nk row
  }
}

// ---------------- 3. context: ctx[d][e] = sum_n exp(nk)-weighted nv; also L ----------------
__global__ __launch_bounds__(256) void k_ctx(const float* __restrict__ kk, const float* __restrict__ vv,
                                             const float* __restrict__ gw, const float* __restrict__ gb,
                                             float* __restrict__ ws, int usePart){
  int chunk = blockIdx.x;  // 64 chunks x 512 tokens
  int bh = blockIdx.y; int b=bh>>2, h=bh&3;
  __shared__ __align__(16) float pk[64][68];
  __shared__ __align__(16) float pv[64][68];
  __shared__ float ctx_s[4096];
  __shared__ float ak[64], bmk[64], av[64], bvv[64], Lacc[64];
  int tid = threadIdx.x;
  if (tid < 64){
    int c = h*64+tid;
    int gik = 8+bh, giv = 16+bh;
    float muk=ws[OFF_MUSR+2*gik], rsk=ws[OFF_MUSR+2*gik+1];
    float muv=ws[OFF_MUSR+2*giv], rsv=ws[OFF_MUSR+2*giv+1];
    float w = gw[c], bb = gb[c];
    float a = rsk*w; ak[tid]=a; bmk[tid]=(bb-muk*a)-ws[OFF_MROW+b*256+c];
    float a2 = rsv*w; av[tid]=a2; bvv[tid]=bb-muv*a2;
    Lacc[tid]=0.f;
  }
  for (int i=tid;i<4096;i+=256) ctx_s[i]=0.f;
  __syncthreads();
  const float* kb = kk + (size_t)b*8388608 + (size_t)h*2097152;
  const float* vb = vv + (size_t)b*8388608 + (size_t)h*2097152;
  float acc[8][8];
  #pragma unroll
  for (int i=0;i<8;++i){
    #pragma unroll
    for (int j=0;j<8;++j) acc[i][j]=0.f;
  }
  float lsum[4] = {0.f,0.f,0.f,0.f};
  int lane = tid&63, wvid = tid>>6;
  int ry = lane>>3, rx = lane&7;
  int nb0 = chunk*512;
  for (int tile=0; tile<8; ++tile){
    int n0 = nb0 + tile*64;
    #pragma unroll
    for (int l=0;l<4;++l){
      int vi = tid + 256*l;
      int d = vi>>4; int t4 = (vi&15)*4;
      const float4 x = *(const float4*)(kb + d*32768 + n0 + t4);
      float e0=__expf(fmaf(x.x,ak[d],bmk[d]));
      float e1=__expf(fmaf(x.y,ak[d],bmk[d]));
      float e2=__expf(fmaf(x.z,ak[d],bmk[d]));
      float e3=__expf(fmaf(x.w,ak[d],bmk[d]));
      pk[t4+0][d]=e0; pk[t4+1][d]=e1; pk[t4+2][d]=e2; pk[t4+3][d]=e3;
      lsum[l] += (e0+e1)+(e2+e3);
      const float4 y = *(const float4*)(vb + d*32768 + n0 + t4);
      pv[t4+0][d]=fmaf(y.x,av[d],bvv[d]);
      pv[t4+1][d]=fmaf(y.y,av[d],bvv[d]);
      pv[t4+2][d]=fmaf(y.z,av[d],bvv[d]);
      pv[t4+3][d]=fmaf(y.w,av[d],bvv[d]);
    }
    __syncthreads();
    int tb = wvid*16;
    #pragma unroll
    for (int t=0;t<16;++t){
      float4 a0 = *(const float4*)&pk[tb+t][8*ry];
      float4 a1 = *(const float4*)&pk[tb+t][8*ry+4];
      float4 b0 = *(const float4*)&pv[tb+t][8*rx];
      float4 b1 = *(const float4*)&pv[tb+t][8*rx+4];
      float aa[8]={a0.x,a0.y,a0.z,a0.w,a1.x,a1.y,a1.z,a1.w};
      float bbx[8]={b0.x,b0.y,b0.z,b0.w,b1.x,b1.y,b1.z,b1.w};
      #pragma unroll
      for (int i=0;i<8;++i){
        #pragma unroll
        for (int j=0;j<8;++j) acc[i][j]=fmaf(aa[i],bbx[j],acc[i][j]);
      }
    }
    __syncthreads();
  }
  #pragma unroll
  for (int l=0;l<4;++l) atomicAdd(&Lacc[(tid+256*l)>>4], lsum[l]);
  #pragma unroll
  for (int i=0;i<8;++i){
    #pragma unroll
    for (int j=0;j<8;++j) atomicAdd(&ctx_s[(8*ry+i)*64 + 8*rx+j], acc[i][j]);
  }
  __syncthreads();
  if (usePart){
    float* cp = ws + OFF_CTXP + (size_t)(chunk*8+bh)*4096;
    for (int i=tid;i<4096;i+=256) cp[i]=ctx_s[i];
    if (tid<64) ws[OFF_LP + (chunk*8+bh)*64 + tid] = Lacc[tid];
  } else {
    float* cp = ws + OFF_CTX + bh*4096;
    for (int i=tid;i<4096;i+=256) atomicAdd(&cp[i], ctx_s[i]);
    if (tid<64) atomicAdd(&ws[OFF_L + bh*64 + tid], Lacc[tid]);
  }
}

// ---------------- 3b. reduce ctx + L partials ----------------
__global__ void k_ctxred(float* __restrict__ ws){
  int i = blockIdx.x*256 + threadIdx.x;
  if (i < 32768){
    float s = 0.f;
    const float* p = ws + OFF_CTXP + i;
    #pragma unroll 8
    for (int c=0;c<64;++c) s += p[(size_t)c*32768];
    ws[OFF_CTX + i] = s;
  } else if (i < 33280){
    int j = i - 32768;
    float s=0.f; const float* p = ws + OFF_LP + j;
    #pragma unroll 8
    for (int c=0;c<64;++c) s += p[c*512];
    ws[OFF_L + j] = s;
  }
}

// ---------------- 4. build (M_b + I)^T and K_b ----------------
__global__ __launch_bounds__(256) void k_weff(const float* __restrict__ w1, const float* __restrict__ ob,
                                              const float* __restrict__ gw, const float* __restrict__ gb,
                                              float* __restrict__ ws){
  int co = blockIdx.x; int b = blockIdx.y;
  int cp = threadIdx.x;
  int hp = cp>>6, dp = cp&63;
  const float* ctx = ws + OFF_CTX + (size_t)(b*4+hp)*4096 + dp*64;
  const float* w1p = w1 + co*256 + hp*64;
  float s = 0.f;
  #pragma unroll 8
  for (int e=0;e<64;++e) s = fmaf(w1p[e], ctx[e], s);
  float L = ws[OFF_L + b*256 + cp];
  float weff = s / L;
  int gi = b*4 + hp;                 // q stats
  float mu = ws[OFF_MUSR+2*gi], rs = ws[OFF_MUSR+2*gi+1];
  float aq = rs*gw[cp]; float bq = gb[cp] - mu*aq;
  float mb = fmaf(weff, aq, (co==cp)?1.f:0.f);   // + identity folds the residual
  ws[OFF_MBT + (size_t)b*65536 + cp*256 + co] = mb;
  float kp = weff*bq;
  for (int o=32;o>0;o>>=1) kp += __shfl_down(kp,o);
  __shared__ float red[4];
  if ((cp&63)==0) red[cp>>6]=kp;
  __syncthreads();
  if (cp==0) ws[OFF_KB + b*256 + co] = ob[co] + ((red[0]+red[1])+(red[2]+red[3]));
}

// ---------------- 5. z = (M_b+I) q + K_b  ->  bf16 ----------------
__global__ __launch_bounds__(256) void k_z(const float* __restrict__ q, float* __restrict__ ws){
  int nt = blockIdx.x, cot = blockIdx.y, b = blockIdx.z;
  int tid = threadIdx.x; int tx = tid&15, wy = tid>>4;
  int n0 = nt*128, co0 = cot*128;
  __shared__ __align__(16) float qs[32][128];
  const float* qb = q + (size_t)b*8388608;
  const float* mbt = ws + OFF_MBT + (size_t)b*65536;
  float acc[8][8];
  #pragma unroll
  for (int i=0;i<8;++i){
    #pragma unroll
    for (int j=0;j<8;++j) acc[i][j]=0.f;
  }
  for (int cc0=0; cc0<256; cc0+=32){
    #pragma unroll
    for (int l=0;l<4;++l){
      int vi = tid + 256*l; int c = vi>>5; int n4 = (vi&31)*4;
      *(float4*)&qs[c][n4] = *(const float4*)(qb + (size_t)(cc0+c)*32768 + n0 + n4);
    }
    __syncthreads();
    #pragma unroll 4
    for (int c=0;c<32;++c){
      float4 q0 = *(const float4*)&qs[c][8*tx];
      float4 q1 = *(const float4*)&qs[c][8*tx+4];
      const float* mr = mbt + (size_t)(cc0+c)*256 + co0 + 8*wy;
      float4 m0 = *(const float4*)mr;
      float4 m1 = *(const float4*)(mr+4);
      float mm[8]={m0.x,m0.y,m0.z,m0.w,m1.x,m1.y,m1.z,m1.w};
      float qq[8]={q0.x,q0.y,q0.z,q0.w,q1.x,q1.y,q1.z,q1.w};
      #pragma unroll
      for (int i=0;i<8;++i){
        #pragma unroll
        for (int j=0;j<8;++j) acc[i][j]=fmaf(mm[i],qq[j],acc[i][j]);
      }
    }
    __syncthreads();
  }
  u16* zp0 = (u16*)(ws + OFF_Z) + (size_t)b*8388608;
  #pragma unroll
  for (int i=0;i<8;++i){
    int co = co0 + 8*wy + i;
    float kb = ws[OFF_KB + b*256 + co];
    uint4 u;
    u.x = (uint32)f2bf(acc[i][0]+kb) | ((uint32)f2bf(acc[i][1]+kb)<<16);
    u.y = (uint32)f2bf(acc[i][2]+kb) | ((uint32)f2bf(acc[i][3]+kb)<<16);
    u.z = (uint32)f2bf(acc[i][4]+kb) | ((uint32)f2bf(acc[i][5]+kb)<<16);
    u.w = (uint32)f2bf(acc[i][6]+kb) | ((uint32)f2bf(acc[i][7]+kb)<<16);
    *(uint4*)(zp0 + (size_t)co*32768 + n0 + 8*tx) = u;
  }
}

// ---------------- 6. dg conv: 3x3x3, 256 -> 3, pad 1 (z in bf16) ----------------
__global__ __launch_bounds__(256) void k_dg(const float* __restrict__ dgw, float* __restrict__ ws, int usePart){
  int tile = blockIdx.x;        // 0..7
  int split = blockIdx.y;       // 0..31 (8 ci each)
  int b = blockIdx.z;
  int d0 = (tile>>1)*8, h0=(tile&1)*16;
  int tid = threadIdx.x;
  int wt = tid&1, hy=(tid>>1)&15, dx=tid>>5;
  __shared__ __align__(16) float zs[2][10][18][36];
  __shared__ __align__(16) float wss[2][27][4];
  const u16* zp = (const u16*)(ws+OFF_Z) + (size_t)b*8388608;
  float acc[3][16];
  #pragma unroll
  for (int o=0;o<3;++o){
    #pragma unroll
    for (int j=0;j<16;++j) acc[o][j]=0.f;
  }
  int cbeg = split*8;
  for (int cc = cbeg; cc < cbeg+8; cc += 2){
    for (int i=tid; i<12240; i+=256){
      int ci = i/6120; int r = i - ci*6120;
      int dz = r/612; int r2 = r - dz*612; int hz = r2/34; int wz = r2 - hz*34;
      int gd = d0+dz-1, gh = h0+hz-1, gwv = wz-1;
      float val = 0.f;
      if (gd>=0 && gd<32 && gh>=0 && gh<32 && gwv>=0 && gwv<32)
        val = bf2f(zp[(size_t)(cc+ci)*32768 + gd*1024 + gh*32 + gwv]);
      zs[ci][dz][hz][wz] = val;
    }
    for (int i=tid;i<216;i+=256){
      int ci=i/108; int r=i-ci*108; int tap=r>>2; int o=r&3;
      wss[ci][tap][o] = (o<3)? dgw[o*6912 + (cc+ci)*27 + tap] : 0.f;
    }
    __syncthreads();
    #pragma unroll
    for (int ci=0;ci<2;++ci){
      #pragma unroll
      for (int kd=0;kd<3;++kd){
        #pragma unroll
        for (int kh=0;kh<3;++kh){
          const float* row = &zs[ci][dx+kd][hy+kh][wt*16];
          float4 p0=*(const float4*)(row), p1=*(const float4*)(row+4);
          float4 p2=*(const float4*)(row+8), p3=*(const float4*)(row+12);
          float2 p4=*(const float2*)(row+16);
          float rv[18]={p0.x,p0.y,p0.z,p0.w,p1.x,p1.y,p1.z,p1.w,
                        p2.x,p2.y,p2.z,p2.w,p3.x,p3.y,p3.z,p3.w,p4.x,p4.y};
          #pragma unroll
          for (int kw=0;kw<3;++kw){
            float4 wv = *(const float4*)&wss[ci][kd*9+kh*3+kw][0];
            #pragma unroll
            for (int j=0;j<16;++j){
              acc[0][j]=fmaf(rv[kw+j],wv.x,acc[0][j]);
              acc[1][j]=fmaf(rv[kw+j],wv.y,acc[1][j]);
              acc[2][j]=fmaf(rv[kw+j],wv.z,acc[2][j]);
            }
          }
        }
      }
    }
    __syncthreads();
  }
  if (usePart){
    float* op = ws + OFF_DGP + (size_t)split*196608 + (size_t)b*98304;
    #pragma unroll
    for (int o=0;o<3;++o){
      int base = o*32768 + (d0+dx)*1024 + (h0+hy)*32 + wt*16;
      *(float4*)&op[base+0]  = make_float4(acc[o][0],acc[o][1],acc[o][2],acc[o][3]);
      *(float4*)&op[base+4]  = make_float4(acc[o][4],acc[o][5],acc[o][6],acc[o][7]);
      *(float4*)&op[base+8]  = make_float4(acc[o][8],acc[o][9],acc[o][10],acc[o][11]);
      *(float4*)&op[base+12] = make_float4(acc[o][12],acc[o][13],acc[o][14],acc[o][15]);
    }
  } else {
    float* op = ws + OFF_DG + (size_t)b*98304;
    #pragma unroll
    for (int o=0;o<3;++o){
      #pragma unroll
      for (int j=0;j<16;++j)
        atomicAdd(&op[o*32768 + (d0+dx)*1024 + (h0+hy)*32 + wt*16 + j], acc[o][j]);
    }
  }
}

__global__ void k_dgred(float* __restrict__ ws){
  int i = blockIdx.x*256 + threadIdx.x; // < 196608
  float s = 0.f;
  const float* p = ws + OFF_DGP + i;
  #pragma unroll 8
  for (int c=0;c<32;++c) s += p[(size_t)c*196608];
  ws[OFF_DG + i] = s;
}

// ---------------- 7. upsample x2 nearest + 3x3x3 conv (3->3), pad 1 ----------------
__global__ __launch_bounds__(256) void k_up(const float* __restrict__ dgb, const float* __restrict__ nlw,
                                            const float* __restrict__ nlb, const float* __restrict__ ws,
                                            float* __restrict__ out){
  int b = blockIdx.y; int tileIdx = blockIdx.x;
  int zt0 = (tileIdx&7)*8, yt0 = ((tileIdx>>3)&7)*8, xt0 = (tileIdx>>6)*4;
  int sx0 = (xt0>>1)-1, sy0 = (yt0>>1)-1, sz0 = (zt0>>1)-1;
  __shared__ float ds[3][4][6][6];
  __shared__ float wl[243];
  const float* dgp = ws + OFF_DG + (size_t)b*98304;
  for (int i=threadIdx.x; i<432; i+=256){
    int ch = i/144; int r = i-ch*144; int sx=r/36; int r2=r-sx*36; int sy=r2/6; int sz=r2-sy*6;
    int gx = sx0+sx, gy = sy0+sy, gz = sz0+sz;
    float v=0.f;
    if (gx>=0&&gx<32&&gy>=0&&gy<32&&gz>=0&&gz<32) v = dgp[ch*32768 + gx*1024 + gy*32 + gz] + dgb[ch];
    ds[ch][sx][sy][sz] = v;
  }
  for (int i=threadIdx.x;i<243;i+=256) wl[i] = nlw[i];
  __syncthreads();
  int zt = threadIdx.x&7, yt=(threadIdx.x>>3)&7, xt=threadIdx.x>>6;
  int x = xt0+xt, y=yt0+yt, zc=zt0+zt;
  float a0=nlb[0], a1=nlb[1], a2=nlb[2];
  #pragma unroll
  for (int i=0;i<3;++i){
    #pragma unroll
    for (int kd=0;kd<3;++kd){
      int sxi = ((x+kd-1)>>1) - sx0;
      #pragma unroll
      for (int kh=0;kh<3;++kh){
        int syi = ((y+kh-1)>>1) - sy0;
        #pragma unroll
        for (int kw=0;kw<3;++kw){
          int szi = ((zc+kw-1)>>1) - sz0;
          float vv = ds[i][sxi][syi][szi];
          int tap = kd*9+kh*3+kw;
          a0 = fmaf(vv, wl[i*27+tap],      a0);
          a1 = fmaf(vv, wl[81+i*27+tap],   a1);
          a2 = fmaf(vv, wl[162+i*27+tap],  a2);
        }
      }
    }
  }
  size_t o0 = (size_t)b*786432 + (size_t)x*4096 + y*64 + zc;
  out[o0] = a0; out[o0+262144] = a1; out[o0+524288] = a2;
}

// ---------------- launch ----------------
extern "C" void kernel_launch(void* const* d_in, const int* in_sizes, int n_in,
                              void* d_out, int out_size, void* d_ws, size_t ws_size,
                              hipStream_t stream){
  const float* q    = (const float*)d_in[0];
  const float* k    = (const float*)d_in[1];
  const float* v    = (const float*)d_in[2];
  const float* gnw  = (const float*)d_in[3];
  const float* gnb  = (const float*)d_in[4];
  const float* outw = (const float*)d_in[5];
  const float* outb = (const float*)d_in[6];
  const float* dgw  = (const float*)d_in[7];
  const float* dgb  = (const float*)d_in[8];
  const float* nlw  = (const float*)d_in[9];
  const float* nlb  = (const float*)d_in[10];
  float* out = (float*)d_out;
  float* ws  = (float*)d_ws;
  int usePart = (ws_size >= (size_t)WS_PART_FLOATS*4) ? 1 : 0;

  (void)hipMemsetAsync(ws, 0, 139264, stream);                       // stats..ctx region
  (void)hipMemsetAsync((void*)(ws + OFF_DG), 0, 196608*4, stream);   // dg final (atomic fallback)

  k_stats   <<<dim3(1536),   dim3(256), 0, stream>>>(q,k,v,ws);
  k_finalize<<<dim3(1),      dim3(512), 0, stream>>>(gnw,gnb,ws);
  k_ctx     <<<dim3(64,8),   dim3(256), 0, stream>>>(k,v,gnw,gnb,ws,usePart);
  if (usePart) k_ctxred<<<dim3(130), dim3(256), 0, stream>>>(ws);
  k_weff    <<<dim3(256,2),  dim3(256), 0, stream>>>(outw,outb,gnw,gnb,ws);
  k_z       <<<dim3(256,2,2),dim3(256), 0, stream>>>(q,ws);
  k_dg      <<<dim3(8,32,2), dim3(256), 0, stream>>>(dgw,ws,usePart);
  if (usePart) k_dgred<<<dim3(768), dim3(256), 0, stream>>>(ws);
  k_up      <<<dim3(1024,2), dim3(256), 0, stream>>>(dgb,nlw,nlb,ws,out);
}

// Round 3
// 507.774 us; speedup vs baseline: 1.1317x; 1.1317x over previous
//
#include <hip/hip_runtime.h>
#include <math.h>

typedef unsigned int uint32;
typedef unsigned short u16;

typedef __bf16 bf16x8 __attribute__((ext_vector_type(8)));
typedef float f32x4 __attribute__((ext_vector_type(4)));

// ---------------- workspace layout (float indices) ----------------
#define OFF_STATS 0        // 48: sum,sumsq per (t=q/k/v, b, g)
#define OFF_MUSR  64       // 48: mu, rsigma
#define OFF_L     128      // 512: softmax denominators per (b,c)
#define OFF_MROW  640      // 512: softmax row max (of nk)
#define OFF_MAXV  1280     // 512: raw-k row max
#define OFF_MINV  1792     // 512: raw-k row min
#define OFF_CTX   2048     // 32768: raw context [b,h][d][e]
#define OFF_MBT   34816    // M' as bf16 [b][co][c'] : 131072 u16 = 65536 float slots
#define OFF_KB    165888   // 512: K_b
#define OFF_Z     167936   // z as bf16: 16777216 u16 = 8388608 float slots
#define OFF_DG    8556544  // 196608: dg conv output (pre-bias)
#define OFF_CTXP  8753152  // 64*8*4096 ctx partials (part mode)
#define OFF_LP    10850304 // 64*8*64 L partials
#define OFF_DGP   8753152  // 32*196608 dg partials (aliases CTXP/LP, consumed earlier)
#define WS_PART_FLOATS 15044608

__device__ __forceinline__ float bf2f(u16 h){ return __uint_as_float(((uint32)h)<<16); }
__device__ __forceinline__ u16 f2bf(float f){ uint32 u=__float_as_uint(f); return (u16)((u + 0x7fffu + ((u>>16)&1u))>>16); }

// ---------------- 1. stats: sum/sumsq per group + per-row min/max of k ----------------
__global__ __launch_bounds__(256) void k_stats(const float* __restrict__ q, const float* __restrict__ k,
                                               const float* __restrict__ v, float* __restrict__ ws){
  int gid = blockIdx.x >> 6;     // 0..23 = t*8 + bg
  int chunk = blockIdx.x & 63;   // row within group
  int t = gid >> 3; int bg = gid & 7;
  const float* src = (t==0)? q : ((t==1)? k : v);
  const float* base = src + (size_t)bg*2097152 + (size_t)chunk*32768;
  int tid = threadIdx.x;
  float s=0.f, ss=0.f, mx=-INFINITY, mn=INFINITY;
  #pragma unroll 4
  for (int it=0; it<32; ++it){
    float4 x = *(const float4*)(base + it*1024 + tid*4);
    s += (x.x+x.y)+(x.z+x.w);
    ss = fmaf(x.x,x.x, fmaf(x.y,x.y, fmaf(x.z,x.z, fmaf(x.w,x.w, ss))));
    mx = fmaxf(mx, fmaxf(fmaxf(x.x,x.y), fmaxf(x.z,x.w)));
    mn = fminf(mn, fminf(fminf(x.x,x.y), fminf(x.z,x.w)));
  }
  for (int o=32;o>0;o>>=1){
    s  += __shfl_down(s,o);  ss += __shfl_down(ss,o);
    mx = fmaxf(mx, __shfl_down(mx,o)); mn = fminf(mn, __shfl_down(mn,o));
  }
  __shared__ float rsum[4], rssq[4], rmx[4], rmn[4];
  int w = tid>>6;
  if ((tid&63)==0){ rsum[w]=s; rssq[w]=ss; rmx[w]=mx; rmn[w]=mn; }
  __syncthreads();
  if (tid==0){
    atomicAdd(&ws[OFF_STATS + gid*2],   (rsum[0]+rsum[1])+(rsum[2]+rsum[3]));
    atomicAdd(&ws[OFF_STATS + gid*2+1], (rssq[0]+rssq[1])+(rssq[2]+rssq[3]));
    if (t==1){
      int r = bg*64 + chunk;  // one block per row -> plain store
      ws[OFF_MAXV + r] = fmaxf(fmaxf(rmx[0],rmx[1]),fmaxf(rmx[2],rmx[3]));
      ws[OFF_MINV + r] = fminf(fminf(rmn[0],rmn[1]),fminf(rmn[2],rmn[3]));
    }
  }
}

// ---------------- 2. finalize: mu/rsigma + softmax row max ----------------
__global__ void k_finalize(const float* __restrict__ gw, const float* __restrict__ gb, float* __restrict__ ws){
  int tid = threadIdx.x;
  if (tid < 24){
    float s=ws[OFF_STATS+2*tid], ss=ws[OFF_STATS+2*tid+1];
    const float inv = 1.f/2097152.f;
    float mu = s*inv;
    float var = ss*inv - mu*mu;
    ws[OFF_MUSR+2*tid]=mu; ws[OFF_MUSR+2*tid+1]=rsqrtf(var+1e-5f);
  }
  __syncthreads();
  if (tid < 512){
    int b=tid>>8, c=tid&255, g=c>>6;
    int gi = 8 + b*4 + g;                       // k-tensor stats
    float mu=ws[OFF_MUSR+2*gi], rs=ws[OFF_MUSR+2*gi+1];
    float a = rs*gw[c]; float beta = gb[c] - mu*a;
    float mx = ws[OFF_MAXV+tid], mn = ws[OFF_MINV+tid];
    ws[OFF_MROW+tid] = (a>=0.f)? fmaf(a,mx,beta) : fmaf(a,mn,beta); // exact max of nk row
  }
}

// ---------------- 3. context: ctx[d][e] = sum_n exp(nk)-weighted nv; also L ----------------
__global__ __launch_bounds__(256) void k_ctx(const float* __restrict__ kk, const float* __restrict__ vv,
                                             const float* __restrict__ gw, const float* __restrict__ gb,
                                             float* __restrict__ ws, int usePart){
  int chunk = blockIdx.x;  // 64 chunks x 512 tokens
  int bh = blockIdx.y; int b=bh>>2, h=bh&3;
  __shared__ __align__(16) float pk[64][68];
  __shared__ __align__(16) float pv[64][68];
  __shared__ float ctx_s[4096];
  __shared__ float ak[64], bmk[64], av[64], bvv[64], Lacc[64];
  int tid = threadIdx.x;
  if (tid < 64){
    int c = h*64+tid;
    int gik = 8+bh, giv = 16+bh;
    float muk=ws[OFF_MUSR+2*gik], rsk=ws[OFF_MUSR+2*gik+1];
    float muv=ws[OFF_MUSR+2*giv], rsv=ws[OFF_MUSR+2*giv+1];
    float w = gw[c], bb = gb[c];
    float a = rsk*w; ak[tid]=a; bmk[tid]=(bb-muk*a)-ws[OFF_MROW+b*256+c];
    float a2 = rsv*w; av[tid]=a2; bvv[tid]=bb-muv*a2;
    Lacc[tid]=0.f;
  }
  for (int i=tid;i<4096;i+=256) ctx_s[i]=0.f;
  __syncthreads();
  const float* kb = kk + (size_t)b*8388608 + (size_t)h*2097152;
  const float* vb = vv + (size_t)b*8388608 + (size_t)h*2097152;
  float acc[8][8];
  #pragma unroll
  for (int i=0;i<8;++i){
    #pragma unroll
    for (int j=0;j<8;++j) acc[i][j]=0.f;
  }
  float lsum[4] = {0.f,0.f,0.f,0.f};
  int lane = tid&63, wvid = tid>>6;
  int ry = lane>>3, rx = lane&7;
  int nb0 = chunk*512;
  for (int tile=0; tile<8; ++tile){
    int n0 = nb0 + tile*64;
    #pragma unroll
    for (int l=0;l<4;++l){
      int vi = tid + 256*l;
      int d = vi>>4; int t4 = (vi&15)*4;
      const float4 x = *(const float4*)(kb + d*32768 + n0 + t4);
      float e0=__expf(fmaf(x.x,ak[d],bmk[d]));
      float e1=__expf(fmaf(x.y,ak[d],bmk[d]));
      float e2=__expf(fmaf(x.z,ak[d],bmk[d]));
      float e3=__expf(fmaf(x.w,ak[d],bmk[d]));
      pk[t4+0][d]=e0; pk[t4+1][d]=e1; pk[t4+2][d]=e2; pk[t4+3][d]=e3;
      lsum[l] += (e0+e1)+(e2+e3);
      const float4 y = *(const float4*)(vb + d*32768 + n0 + t4);
      pv[t4+0][d]=fmaf(y.x,av[d],bvv[d]);
      pv[t4+1][d]=fmaf(y.y,av[d],bvv[d]);
      pv[t4+2][d]=fmaf(y.z,av[d],bvv[d]);
      pv[t4+3][d]=fmaf(y.w,av[d],bvv[d]);
    }
    __syncthreads();
    int tb = wvid*16;
    #pragma unroll
    for (int t=0;t<16;++t){
      float4 a0 = *(const float4*)&pk[tb+t][8*ry];
      float4 a1 = *(const float4*)&pk[tb+t][8*ry+4];
      float4 b0 = *(const float4*)&pv[tb+t][8*rx];
      float4 b1 = *(const float4*)&pv[tb+t][8*rx+4];
      float aa[8]={a0.x,a0.y,a0.z,a0.w,a1.x,a1.y,a1.z,a1.w};
      float bbx[8]={b0.x,b0.y,b0.z,b0.w,b1.x,b1.y,b1.z,b1.w};
      #pragma unroll
      for (int i=0;i<8;++i){
        #pragma unroll
        for (int j=0;j<8;++j) acc[i][j]=fmaf(aa[i],bbx[j],acc[i][j]);
      }
    }
    __syncthreads();
  }
  #pragma unroll
  for (int l=0;l<4;++l) atomicAdd(&Lacc[(tid+256*l)>>4], lsum[l]);
  #pragma unroll
  for (int i=0;i<8;++i){
    #pragma unroll
    for (int j=0;j<8;++j) atomicAdd(&ctx_s[(8*ry+i)*64 + 8*rx+j], acc[i][j]);
  }
  __syncthreads();
  if (usePart){
    float* cp = ws + OFF_CTXP + (size_t)(chunk*8+bh)*4096;
    for (int i=tid;i<4096;i+=256) cp[i]=ctx_s[i];
    if (tid<64) ws[OFF_LP + (chunk*8+bh)*64 + tid] = Lacc[tid];
  } else {
    float* cp = ws + OFF_CTX + bh*4096;
    for (int i=tid;i<4096;i+=256) atomicAdd(&cp[i], ctx_s[i]);
    if (tid<64) atomicAdd(&ws[OFF_L + bh*64 + tid], Lacc[tid]);
  }
}

// ---------------- 3b. reduce ctx + L partials ----------------
__global__ void k_ctxred(float* __restrict__ ws){
  int i = blockIdx.x*256 + threadIdx.x;
  if (i < 32768){
    float s = 0.f;
    const float* p = ws + OFF_CTXP + i;
    #pragma unroll 8
    for (int c=0;c<64;++c) s += p[(size_t)c*32768];
    ws[OFF_CTX + i] = s;
  } else if (i < 33280){
    int j = i - 32768;
    float s=0.f; const float* p = ws + OFF_LP + j;
    #pragma unroll 8
    for (int c=0;c<64;++c) s += p[c*512];
    ws[OFF_L + j] = s;
  }
}

// ---------------- 4. build M' (bf16, [b][co][c']) and K_b ----------------
__global__ __launch_bounds__(256) void k_weff(const float* __restrict__ w1, const float* __restrict__ ob,
                                              const float* __restrict__ gw, const float* __restrict__ gb,
                                              float* __restrict__ ws){
  int co = blockIdx.x; int b = blockIdx.y;
  int cp = threadIdx.x;
  int hp = cp>>6, dp = cp&63;
  const float* ctx = ws + OFF_CTX + (size_t)(b*4+hp)*4096 + dp*64;
  const float* w1p = w1 + co*256 + hp*64;
  float s = 0.f;
  #pragma unroll 8
  for (int e=0;e<64;++e) s = fmaf(w1p[e], ctx[e], s);
  float L = ws[OFF_L + b*256 + cp];
  float weff = s / L;
  int gi = b*4 + hp;                 // q stats
  float mu = ws[OFF_MUSR+2*gi], rs = ws[OFF_MUSR+2*gi+1];
  float aq = rs*gw[cp]; float bq = gb[cp] - mu*aq;
  // M' WITHOUT identity: residual q added in fp32 in k_z epilogue
  u16* mbp = (u16*)(ws + OFF_MBT);
  mbp[(size_t)b*65536 + (size_t)co*256 + cp] = f2bf(weff*aq);
  float kp = weff*bq;
  for (int o=32;o>0;o>>=1) kp += __shfl_down(kp,o);
  __shared__ float red[4];
  if ((cp&63)==0) red[cp>>6]=kp;
  __syncthreads();
  if (cp==0) ws[OFF_KB + b*256 + co] = ob[co] + ((red[0]+red[1])+(red[2]+red[3]));
}

// ---------------- 5. z = q + M' q + K_b  (MFMA bf16), z -> bf16 ----------------
// block: 128co x 128n tile; 4 waves 2x2 (64x64 each); K=256 in 4 tiles of 64.
// LDS: A [128co][72] bf16, B [128n][72] bf16 (q transposed), epilogue C [128][136] bf16 aliased.
__global__ __launch_bounds__(256, 4) void k_z(const float* __restrict__ q, float* __restrict__ ws){
  extern __shared__ char smem[];
  u16* As = (u16*)smem;                 // 128*72*2 = 18432 B
  u16* Bs = As + 128*72;                // +18432 B
  u16* Cs = (u16*)smem;                 // epilogue alias: 128*136*2 = 34816 B
  int nt = blockIdx.x, cot = blockIdx.y, b = blockIdx.z;
  int n0 = nt*128, co0 = cot*128;
  int tid = threadIdx.x;
  int lane = tid & 63, wv = tid >> 6;
  int m16 = lane & 15, quad = lane >> 4;
  int wco = (wv>>1)*64, wn = (wv&1)*64;
  const u16* mb = (const u16*)(ws + OFF_MBT) + (size_t)b*65536;
  const float* qb = q + (size_t)b*8388608;
  f32x4 acc[4][4];
  #pragma unroll
  for (int i=0;i<4;++i){
    #pragma unroll
    for (int j=0;j<4;++j) acc[i][j] = 0.f;
  }
  int r2 = tid>>1, seg = tid&1;
  int nq = tid & 31, cp0 = tid >> 5;
  for (int kt=0; kt<4; ++kt){
    { // A stage: 128 rows x 64 k bf16
      const u16* src = mb + (size_t)(co0 + r2)*256 + kt*64 + seg*32;
      u16* dst = As + r2*72 + seg*32;
      uint4 w0 = *(const uint4*)(src);
      uint4 w1 = *(const uint4*)(src+8);
      uint4 w2 = *(const uint4*)(src+16);
      uint4 w3 = *(const uint4*)(src+24);
      *(uint4*)(dst)    = w0; *(uint4*)(dst+8)  = w1;
      *(uint4*)(dst+16) = w2; *(uint4*)(dst+24) = w3;
    }
    // B stage: q[c][n] -> Bs[n][c-local] bf16 (transpose, packed dword pairs)
    #pragma unroll
    for (int p=0;p<4;++p){
      int cpair = cp0 + 8*p;
      int c = kt*64 + 2*cpair;
      const float* q0 = qb + (size_t)c*32768 + n0 + nq;
      const float* q1 = q0 + 32768;
      #pragma unroll
      for (int i=0;i<4;++i){
        float a  = q0[32*i];
        float bb = q1[32*i];
        uint32 dw = (uint32)f2bf(a) | ((uint32)f2bf(bb)<<16);
        *(uint32*)(Bs + (nq+32*i)*72 + 2*cpair) = dw;
      }
    }
    __syncthreads();
    #pragma unroll
    for (int ks=0; ks<2; ++ks){
      bf16x8 af[4], bfr[4];
      #pragma unroll
      for (int i=0;i<4;++i) af[i]  = *(const bf16x8*)(As + (wco + i*16 + m16)*72 + ks*32 + quad*8);
      #pragma unroll
      for (int j=0;j<4;++j) bfr[j] = *(const bf16x8*)(Bs + (wn + j*16 + m16)*72 + ks*32 + quad*8);
      #pragma unroll
      for (int i=0;i<4;++i){
        #pragma unroll
        for (int j=0;j<4;++j)
          acc[i][j] = __builtin_amdgcn_mfma_f32_16x16x32_bf16(af[i], bfr[j], acc[i][j], 0, 0, 0);
      }
    }
    __syncthreads();
  }
  // epilogue: acc -> Cs (bf16, [co][n]), then coalesced read-back + fp32 q residual + Kb
  #pragma unroll
  for (int i=0;i<4;++i){
    #pragma unroll
    for (int r=0;r<4;++r){
      int row = wco + i*16 + quad*4 + r;
      #pragma unroll
      for (int j=0;j<4;++j)
        Cs[row*136 + wn + j*16 + m16] = f2bf(acc[i][j][r]);
    }
  }
  __syncthreads();
  {
    int co = co0 + r2;
    float kbv = ws[OFF_KB + b*256 + co];
    u16* zp = (u16*)(ws + OFF_Z) + (size_t)b*8388608 + (size_t)co*32768 + n0 + seg*64;
    const float* qr = qb + (size_t)co*32768 + n0 + seg*64;
    #pragma unroll
    for (int ch=0; ch<8; ++ch){
      uint4 cv = *(const uint4*)(Cs + r2*136 + seg*64 + ch*8);
      float4 qa = *(const float4*)(qr + ch*8);
      float4 qc = *(const float4*)(qr + ch*8 + 4);
      float z0 = qa.x + bf2f((u16)(cv.x&0xffff)) + kbv;
      float z1 = qa.y + bf2f((u16)(cv.x>>16))    + kbv;
      float z2 = qa.z + bf2f((u16)(cv.y&0xffff)) + kbv;
      float z3 = qa.w + bf2f((u16)(cv.y>>16))    + kbv;
      float z4 = qc.x + bf2f((u16)(cv.z&0xffff)) + kbv;
      float z5 = qc.y + bf2f((u16)(cv.z>>16))    + kbv;
      float z6 = qc.z + bf2f((u16)(cv.w&0xffff)) + kbv;
      float z7 = qc.w + bf2f((u16)(cv.w>>16))    + kbv;
      uint4 u;
      u.x = (uint32)f2bf(z0) | ((uint32)f2bf(z1)<<16);
      u.y = (uint32)f2bf(z2) | ((uint32)f2bf(z3)<<16);
      u.z = (uint32)f2bf(z4) | ((uint32)f2bf(z5)<<16);
      u.w = (uint32)f2bf(z6) | ((uint32)f2bf(z7)<<16);
      *(uint4*)(zp + ch*8) = u;
    }
  }
}

// ---------------- 6. dg conv: 3x3x3, 256 -> 3, pad 1 (z in bf16) ----------------
__global__ __launch_bounds__(256) void k_dg(const float* __restrict__ dgw, float* __restrict__ ws, int usePart){
  int tile = blockIdx.x;        // 0..7
  int split = blockIdx.y;       // 0..31 (8 ci each)
  int b = blockIdx.z;
  int d0 = (tile>>1)*8, h0=(tile&1)*16;
  int tid = threadIdx.x;
  int wt = tid&1, hy=(tid>>1)&15, dx=tid>>5;
  __shared__ __align__(16) float zs[2][10][18][36];
  __shared__ __align__(16) float wss[2][27][4];
  const u16* zp = (const u16*)(ws+OFF_Z) + (size_t)b*8388608;
  float acc[3][16];
  #pragma unroll
  for (int o=0;o<3;++o){
    #pragma unroll
    for (int j=0;j<16;++j) acc[o][j]=0.f;
  }
  int cbeg = split*8;
  for (int cc = cbeg; cc < cbeg+8; cc += 2){
    for (int i=tid; i<12240; i+=256){
      int ci = i/6120; int r = i - ci*6120;
      int dz = r/612; int rr = r - dz*612; int hz = rr/34; int wz = rr - hz*34;
      int gd = d0+dz-1, gh = h0+hz-1, gwv = wz-1;
      float val = 0.f;
      if (gd>=0 && gd<32 && gh>=0 && gh<32 && gwv>=0 && gwv<32)
        val = bf2f(zp[(size_t)(cc+ci)*32768 + gd*1024 + gh*32 + gwv]);
      zs[ci][dz][hz][wz] = val;
    }
    for (int i=tid;i<216;i+=256){
      int ci=i/108; int r=i-ci*108; int tap=r>>2; int o=r&3;
      wss[ci][tap][o] = (o<3)? dgw[o*6912 + (cc+ci)*27 + tap] : 0.f;
    }
    __syncthreads();
    #pragma unroll
    for (int ci=0;ci<2;++ci){
      #pragma unroll
      for (int kd=0;kd<3;++kd){
        #pragma unroll
        for (int kh=0;kh<3;++kh){
          const float* row = &zs[ci][dx+kd][hy+kh][wt*16];
          float4 p0=*(const float4*)(row), p1=*(const float4*)(row+4);
          float4 p2=*(const float4*)(row+8), p3=*(const float4*)(row+12);
          float2 p4=*(const float2*)(row+16);
          float rv[18]={p0.x,p0.y,p0.z,p0.w,p1.x,p1.y,p1.z,p1.w,
                        p2.x,p2.y,p2.z,p2.w,p3.x,p3.y,p3.z,p3.w,p4.x,p4.y};
          #pragma unroll
          for (int kw=0;kw<3;++kw){
            float4 wv = *(const float4*)&wss[ci][kd*9+kh*3+kw][0];
            #pragma unroll
            for (int j=0;j<16;++j){
              acc[0][j]=fmaf(rv[kw+j],wv.x,acc[0][j]);
              acc[1][j]=fmaf(rv[kw+j],wv.y,acc[1][j]);
              acc[2][j]=fmaf(rv[kw+j],wv.z,acc[2][j]);
            }
          }
        }
      }
    }
    __syncthreads();
  }
  if (usePart){
    float* op = ws + OFF_DGP + (size_t)split*196608 + (size_t)b*98304;
    #pragma unroll
    for (int o=0;o<3;++o){
      int base = o*32768 + (d0+dx)*1024 + (h0+hy)*32 + wt*16;
      *(float4*)&op[base+0]  = make_float4(acc[o][0],acc[o][1],acc[o][2],acc[o][3]);
      *(float4*)&op[base+4]  = make_float4(acc[o][4],acc[o][5],acc[o][6],acc[o][7]);
      *(float4*)&op[base+8]  = make_float4(acc[o][8],acc[o][9],acc[o][10],acc[o][11]);
      *(float4*)&op[base+12] = make_float4(acc[o][12],acc[o][13],acc[o][14],acc[o][15]);
    }
  } else {
    float* op = ws + OFF_DG + (size_t)b*98304;
    #pragma unroll
    for (int o=0;o<3;++o){
      #pragma unroll
      for (int j=0;j<16;++j)
        atomicAdd(&op[o*32768 + (d0+dx)*1024 + (h0+hy)*32 + wt*16 + j], acc[o][j]);
    }
  }
}

__global__ void k_dgred(float* __restrict__ ws){
  int i = blockIdx.x*256 + threadIdx.x; // < 196608
  float s = 0.f;
  const float* p = ws + OFF_DGP + i;
  #pragma unroll 8
  for (int c=0;c<32;++c) s += p[(size_t)c*196608];
  ws[OFF_DG + i] = s;
}

// ---------------- 7. upsample x2 nearest + 3x3x3 conv (3->3), pad 1 ----------------
__global__ __launch_bounds__(256) void k_up(const float* __restrict__ dgb, const float* __restrict__ nlw,
                                            const float* __restrict__ nlb, const float* __restrict__ ws,
                                            float* __restrict__ out){
  int b = blockIdx.y; int tileIdx = blockIdx.x;
  int zt0 = (tileIdx&7)*8, yt0 = ((tileIdx>>3)&7)*8, xt0 = (tileIdx>>6)*4;
  int sx0 = (xt0>>1)-1, sy0 = (yt0>>1)-1, sz0 = (zt0>>1)-1;
  __shared__ float ds[3][4][6][6];
  __shared__ float wl[243];
  const float* dgp = ws + OFF_DG + (size_t)b*98304;
  for (int i=threadIdx.x; i<432; i+=256){
    int ch = i/144; int r = i-ch*144; int sx=r/36; int rr=r-sx*36; int sy=rr/6; int sz=rr-sy*6;
    int gx = sx0+sx, gy = sy0+sy, gz = sz0+sz;
    float v=0.f;
    if (gx>=0&&gx<32&&gy>=0&&gy<32&&gz>=0&&gz<32) v = dgp[ch*32768 + gx*1024 + gy*32 + gz] + dgb[ch];
    ds[ch][sx][sy][sz] = v;
  }
  for (int i=threadIdx.x;i<243;i+=256) wl[i] = nlw[i];
  __syncthreads();
  int zt = threadIdx.x&7, yt=(threadIdx.x>>3)&7, xt=threadIdx.x>>6;
  int x = xt0+xt, y=yt0+yt, zc=zt0+zt;
  float a0=nlb[0], a1=nlb[1], a2=nlb[2];
  #pragma unroll
  for (int i=0;i<3;++i){
    #pragma unroll
    for (int kd=0;kd<3;++kd){
      int sxi = ((x+kd-1)>>1) - sx0;
      #pragma unroll
      for (int kh=0;kh<3;++kh){
        int syi = ((y+kh-1)>>1) - sy0;
        #pragma unroll
        for (int kw=0;kw<3;++kw){
          int szi = ((zc+kw-1)>>1) - sz0;
          float vv = ds[i][sxi][syi][szi];
          int tap = kd*9+kh*3+kw;
          a0 = fmaf(vv, wl[i*27+tap],      a0);
          a1 = fmaf(vv, wl[81+i*27+tap],   a1);
          a2 = fmaf(vv, wl[162+i*27+tap],  a2);
        }
      }
    }
  }
  size_t o0 = (size_t)b*786432 + (size_t)x*4096 + y*64 + zc;
  out[o0] = a0; out[o0+262144] = a1; out[o0+524288] = a2;
}

// ---------------- launch ----------------
extern "C" void kernel_launch(void* const* d_in, const int* in_sizes, int n_in,
                              void* d_out, int out_size, void* d_ws, size_t ws_size,
                              hipStream_t stream){
  const float* q    = (const float*)d_in[0];
  const float* k    = (const float*)d_in[1];
  const float* v    = (const float*)d_in[2];
  const float* gnw  = (const float*)d_in[3];
  const float* gnb  = (const float*)d_in[4];
  const float* outw = (const float*)d_in[5];
  const float* outb = (const float*)d_in[6];
  const float* dgw  = (const float*)d_in[7];
  const float* dgb  = (const float*)d_in[8];
  const float* nlw  = (const float*)d_in[9];
  const float* nlb  = (const float*)d_in[10];
  float* out = (float*)d_out;
  float* ws  = (float*)d_ws;
  int usePart = (ws_size >= (size_t)WS_PART_FLOATS*4) ? 1 : 0;

  (void)hipMemsetAsync(ws, 0, 139264, stream);                       // stats..ctx region
  (void)hipMemsetAsync((void*)(ws + OFF_DG), 0, 196608*4, stream);   // dg final (atomic fallback)

  k_stats   <<<dim3(1536),   dim3(256), 0, stream>>>(q,k,v,ws);
  k_finalize<<<dim3(1),      dim3(512), 0, stream>>>(gnw,gnb,ws);
  k_ctx     <<<dim3(64,8),   dim3(256), 0, stream>>>(k,v,gnw,gnb,ws,usePart);
  if (usePart) k_ctxred<<<dim3(130), dim3(256), 0, stream>>>(ws);
  k_weff    <<<dim3(256,2),  dim3(256), 0, stream>>>(outw,outb,gnw,gnb,ws);
  k_z       <<<dim3(256,2,2),dim3(256), 36864, stream>>>(q,ws);
  k_dg      <<<dim3(8,32,2), dim3(256), 0, stream>>>(dgw,ws,usePart);
  if (usePart) k_dgred<<<dim3(768), dim3(256), 0, stream>>>(ws);
  k_up      <<<dim3(1024,2), dim3(256), 0, stream>>>(dgb,nlw,nlb,ws,out);
}

// Round 4
// 457.960 us; speedup vs baseline: 1.2548x; 1.1088x over previous
//
#include <hip/hip_runtime.h>
#include <math.h>

typedef unsigned int uint32;
typedef unsigned short u16;

typedef __bf16 bf16x8 __attribute__((ext_vector_type(8)));
typedef float f32x4 __attribute__((ext_vector_type(4)));

// ---------------- workspace layout (float indices) ----------------
#define OFF_STATS 0        // 48: sum,sumsq per (t=q/k/v, b, g)
#define OFF_MUSR  64       // 48: mu, rsigma
#define OFF_L     128      // 512: softmax denominators per (b,c)
#define OFF_MROW  640      // 512: softmax row max (of nk)
#define OFF_MAXV  1280     // 512: raw-k row max
#define OFF_MINV  1792     // 512: raw-k row min
#define OFF_CTX   2048     // 32768: raw context [b,h][d][e]
#define OFF_MBT   34816    // M' as bf16 [b][co][c'] : 131072 u16 = 65536 float slots
#define OFF_KB    165888   // 512: K_b
#define OFF_Z     167936   // z as bf16: 16777216 u16 = 8388608 float slots
#define OFF_DG    8556544  // 196608: dg conv output (pre-bias)
#define OFF_CTXP  8753152  // 64*8*4096 ctx partials (part mode)
#define OFF_LP    10850304 // 64*8*64 L partials
#define OFF_DGP   8753152  // 32*196608 dg partials (aliases CTXP/LP, consumed earlier)
#define WS_PART_FLOATS 15044608

__device__ __forceinline__ float bf2f(u16 h){ return __uint_as_float(((uint32)h)<<16); }
__device__ __forceinline__ u16 f2bf(float f){ uint32 u=__float_as_uint(f); return (u16)((u + 0x7fffu + ((u>>16)&1u))>>16); }

// ---------------- 1. stats: sum/sumsq per group + per-row min/max of k ----------------
__global__ __launch_bounds__(256) void k_stats(const float* __restrict__ q, const float* __restrict__ k,
                                               const float* __restrict__ v, float* __restrict__ ws){
  int gid = blockIdx.x >> 6;     // 0..23 = t*8 + bg
  int chunk = blockIdx.x & 63;   // row within group
  int t = gid >> 3; int bg = gid & 7;
  const float* src = (t==0)? q : ((t==1)? k : v);
  const float* base = src + (size_t)bg*2097152 + (size_t)chunk*32768;
  int tid = threadIdx.x;
  float s=0.f, ss=0.f, mx=-INFINITY, mn=INFINITY;
  #pragma unroll 4
  for (int it=0; it<32; ++it){
    float4 x = *(const float4*)(base + it*1024 + tid*4);
    s += (x.x+x.y)+(x.z+x.w);
    ss = fmaf(x.x,x.x, fmaf(x.y,x.y, fmaf(x.z,x.z, fmaf(x.w,x.w, ss))));
    mx = fmaxf(mx, fmaxf(fmaxf(x.x,x.y), fmaxf(x.z,x.w)));
    mn = fminf(mn, fminf(fminf(x.x,x.y), fminf(x.z,x.w)));
  }
  for (int o=32;o>0;o>>=1){
    s  += __shfl_down(s,o);  ss += __shfl_down(ss,o);
    mx = fmaxf(mx, __shfl_down(mx,o)); mn = fminf(mn, __shfl_down(mn,o));
  }
  __shared__ float rsum[4], rssq[4], rmx[4], rmn[4];
  int w = tid>>6;
  if ((tid&63)==0){ rsum[w]=s; rssq[w]=ss; rmx[w]=mx; rmn[w]=mn; }
  __syncthreads();
  if (tid==0){
    atomicAdd(&ws[OFF_STATS + gid*2],   (rsum[0]+rsum[1])+(rsum[2]+rsum[3]));
    atomicAdd(&ws[OFF_STATS + gid*2+1], (rssq[0]+rssq[1])+(rssq[2]+rssq[3]));
    if (t==1){
      int r = bg*64 + chunk;  // one block per row -> plain store
      ws[OFF_MAXV + r] = fmaxf(fmaxf(rmx[0],rmx[1]),fmaxf(rmx[2],rmx[3]));
      ws[OFF_MINV + r] = fminf(fminf(rmn[0],rmn[1]),fminf(rmn[2],rmn[3]));
    }
  }
}

// ---------------- 2. finalize: mu/rsigma + softmax row max ----------------
__global__ void k_finalize(const float* __restrict__ gw, const float* __restrict__ gb, float* __restrict__ ws){
  int tid = threadIdx.x;
  if (tid < 24){
    float s=ws[OFF_STATS+2*tid], ss=ws[OFF_STATS+2*tid+1];
    const float inv = 1.f/2097152.f;
    float mu = s*inv;
    float var = ss*inv - mu*mu;
    ws[OFF_MUSR+2*tid]=mu; ws[OFF_MUSR+2*tid+1]=rsqrtf(var+1e-5f);
  }
  __syncthreads();
  if (tid < 512){
    int b=tid>>8, c=tid&255, g=c>>6;
    int gi = 8 + b*4 + g;                       // k-tensor stats
    float mu=ws[OFF_MUSR+2*gi], rs=ws[OFF_MUSR+2*gi+1];
    float a = rs*gw[c]; float beta = gb[c] - mu*a;
    float mx = ws[OFF_MAXV+tid], mn = ws[OFF_MINV+tid];
    ws[OFF_MROW+tid] = (a>=0.f)? fmaf(a,mx,beta) : fmaf(a,mn,beta); // exact max of nk row
  }
}

// ---------------- 3. context: ctx[d][e] = sum_n exp(nk)-weighted nv; also L ----------------
__global__ __launch_bounds__(256) void k_ctx(const float* __restrict__ kk, const float* __restrict__ vv,
                                             const float* __restrict__ gw, const float* __restrict__ gb,
                                             float* __restrict__ ws, int usePart){
  int chunk = blockIdx.x;  // 64 chunks x 512 tokens
  int bh = blockIdx.y; int b=bh>>2, h=bh&3;
  __shared__ __align__(16) float pk[64][68];
  __shared__ __align__(16) float pv[64][68];
  __shared__ float ctx_s[4096];
  __shared__ float ak[64], bmk[64], av[64], bvv[64], Lacc[64];
  int tid = threadIdx.x;
  if (tid < 64){
    int c = h*64+tid;
    int gik = 8+bh, giv = 16+bh;
    float muk=ws[OFF_MUSR+2*gik], rsk=ws[OFF_MUSR+2*gik+1];
    float muv=ws[OFF_MUSR+2*giv], rsv=ws[OFF_MUSR+2*giv+1];
    float w = gw[c], bb = gb[c];
    float a = rsk*w; ak[tid]=a; bmk[tid]=(bb-muk*a)-ws[OFF_MROW+b*256+c];
    float a2 = rsv*w; av[tid]=a2; bvv[tid]=bb-muv*a2;
    Lacc[tid]=0.f;
  }
  for (int i=tid;i<4096;i+=256) ctx_s[i]=0.f;
  __syncthreads();
  const float* kb = kk + (size_t)b*8388608 + (size_t)h*2097152;
  const float* vb = vv + (size_t)b*8388608 + (size_t)h*2097152;
  float acc[8][8];
  #pragma unroll
  for (int i=0;i<8;++i){
    #pragma unroll
    for (int j=0;j<8;++j) acc[i][j]=0.f;
  }
  float lsum[4] = {0.f,0.f,0.f,0.f};
  int lane = tid&63, wvid = tid>>6;
  int ry = lane>>3, rx = lane&7;
  int nb0 = chunk*512;
  for (int tile=0; tile<8; ++tile){
    int n0 = nb0 + tile*64;
    #pragma unroll
    for (int l=0;l<4;++l){
      int vi = tid + 256*l;
      int d = vi>>4; int t4 = (vi&15)*4;
      const float4 x = *(const float4*)(kb + d*32768 + n0 + t4);
      float e0=__expf(fmaf(x.x,ak[d],bmk[d]));
      float e1=__expf(fmaf(x.y,ak[d],bmk[d]));
      float e2=__expf(fmaf(x.z,ak[d],bmk[d]));
      float e3=__expf(fmaf(x.w,ak[d],bmk[d]));
      pk[t4+0][d]=e0; pk[t4+1][d]=e1; pk[t4+2][d]=e2; pk[t4+3][d]=e3;
      lsum[l] += (e0+e1)+(e2+e3);
      const float4 y = *(const float4*)(vb + d*32768 + n0 + t4);
      pv[t4+0][d]=fmaf(y.x,av[d],bvv[d]);
      pv[t4+1][d]=fmaf(y.y,av[d],bvv[d]);
      pv[t4+2][d]=fmaf(y.z,av[d],bvv[d]);
      pv[t4+3][d]=fmaf(y.w,av[d],bvv[d]);
    }
    __syncthreads();
    int tb = wvid*16;
    #pragma unroll
    for (int t=0;t<16;++t){
      float4 a0 = *(const float4*)&pk[tb+t][8*ry];
      float4 a1 = *(const float4*)&pk[tb+t][8*ry+4];
      float4 b0 = *(const float4*)&pv[tb+t][8*rx];
      float4 b1 = *(const float4*)&pv[tb+t][8*rx+4];
      float aa[8]={a0.x,a0.y,a0.z,a0.w,a1.x,a1.y,a1.z,a1.w};
      float bbx[8]={b0.x,b0.y,b0.z,b0.w,b1.x,b1.y,b1.z,b1.w};
      #pragma unroll
      for (int i=0;i<8;++i){
        #pragma unroll
        for (int j=0;j<8;++j) acc[i][j]=fmaf(aa[i],bbx[j],acc[i][j]);
      }
    }
    __syncthreads();
  }
  #pragma unroll
  for (int l=0;l<4;++l) atomicAdd(&Lacc[(tid+256*l)>>4], lsum[l]);
  #pragma unroll
  for (int i=0;i<8;++i){
    #pragma unroll
    for (int j=0;j<8;++j) atomicAdd(&ctx_s[(8*ry+i)*64 + 8*rx+j], acc[i][j]);
  }
  __syncthreads();
  if (usePart){
    float* cp = ws + OFF_CTXP + (size_t)(chunk*8+bh)*4096;
    for (int i=tid;i<4096;i+=256) cp[i]=ctx_s[i];
    if (tid<64) ws[OFF_LP + (chunk*8+bh)*64 + tid] = Lacc[tid];
  } else {
    float* cp = ws + OFF_CTX + bh*4096;
    for (int i=tid;i<4096;i+=256) atomicAdd(&cp[i], ctx_s[i]);
    if (tid<64) atomicAdd(&ws[OFF_L + bh*64 + tid], Lacc[tid]);
  }
}

// ---------------- 3b. reduce ctx + L partials ----------------
__global__ void k_ctxred(float* __restrict__ ws){
  int i = blockIdx.x*256 + threadIdx.x;
  if (i < 32768){
    float s = 0.f;
    const float* p = ws + OFF_CTXP + i;
    #pragma unroll 8
    for (int c=0;c<64;++c) s += p[(size_t)c*32768];
    ws[OFF_CTX + i] = s;
  } else if (i < 33280){
    int j = i - 32768;
    float s=0.f; const float* p = ws + OFF_LP + j;
    #pragma unroll 8
    for (int c=0;c<64;++c) s += p[c*512];
    ws[OFF_L + j] = s;
  }
}

// ---------------- 4. build M' (bf16, [b][co][c']) and K_b ----------------
__global__ __launch_bounds__(256) void k_weff(const float* __restrict__ w1, const float* __restrict__ ob,
                                              const float* __restrict__ gw, const float* __restrict__ gb,
                                              float* __restrict__ ws){
  int co = blockIdx.x; int b = blockIdx.y;
  int cp = threadIdx.x;
  int hp = cp>>6, dp = cp&63;
  const float* ctx = ws + OFF_CTX + (size_t)(b*4+hp)*4096 + dp*64;
  const float* w1p = w1 + co*256 + hp*64;
  float s = 0.f;
  #pragma unroll 8
  for (int e=0;e<64;++e) s = fmaf(w1p[e], ctx[e], s);
  float L = ws[OFF_L + b*256 + cp];
  float weff = s / L;
  int gi = b*4 + hp;                 // q stats
  float mu = ws[OFF_MUSR+2*gi], rs = ws[OFF_MUSR+2*gi+1];
  float aq = rs*gw[cp]; float bq = gb[cp] - mu*aq;
  // M' WITHOUT identity: residual q added in fp32 in k_z epilogue
  u16* mbp = (u16*)(ws + OFF_MBT);
  mbp[(size_t)b*65536 + (size_t)co*256 + cp] = f2bf(weff*aq);
  float kp = weff*bq;
  for (int o=32;o>0;o>>=1) kp += __shfl_down(kp,o);
  __shared__ float red[4];
  if ((cp&63)==0) red[cp>>6]=kp;
  __syncthreads();
  if (cp==0) ws[OFF_KB + b*256 + co] = ob[co] + ((red[0]+red[1])+(red[2]+red[3]));
}

// ---------------- 5. z = q + M' q + K_b  (MFMA bf16), z -> bf16 ----------------
__global__ __launch_bounds__(256, 4) void k_z(const float* __restrict__ q, float* __restrict__ ws){
  extern __shared__ char smem[];
  u16* As = (u16*)smem;                 // 128*72*2 = 18432 B
  u16* Bs = As + 128*72;                // +18432 B
  u16* Cs = (u16*)smem;                 // epilogue alias: 128*136*2 = 34816 B
  int nt = blockIdx.x, cot = blockIdx.y, b = blockIdx.z;
  int n0 = nt*128, co0 = cot*128;
  int tid = threadIdx.x;
  int lane = tid & 63, wv = tid >> 6;
  int m16 = lane & 15, quad = lane >> 4;
  int wco = (wv>>1)*64, wn = (wv&1)*64;
  const u16* mb = (const u16*)(ws + OFF_MBT) + (size_t)b*65536;
  const float* qb = q + (size_t)b*8388608;
  f32x4 acc[4][4];
  #pragma unroll
  for (int i=0;i<4;++i){
    #pragma unroll
    for (int j=0;j<4;++j) acc[i][j] = 0.f;
  }
  int r2 = tid>>1, seg = tid&1;
  int nq = tid & 31, cp0 = tid >> 5;
  for (int kt=0; kt<4; ++kt){
    { // A stage: 128 rows x 64 k bf16
      const u16* src = mb + (size_t)(co0 + r2)*256 + kt*64 + seg*32;
      u16* dst = As + r2*72 + seg*32;
      uint4 w0 = *(const uint4*)(src);
      uint4 w1 = *(const uint4*)(src+8);
      uint4 w2 = *(const uint4*)(src+16);
      uint4 w3 = *(const uint4*)(src+24);
      *(uint4*)(dst)    = w0; *(uint4*)(dst+8)  = w1;
      *(uint4*)(dst+16) = w2; *(uint4*)(dst+24) = w3;
    }
    // B stage: q[c][n] -> Bs[n][c-local] bf16 (transpose, packed dword pairs)
    #pragma unroll
    for (int p=0;p<4;++p){
      int cpair = cp0 + 8*p;
      int c = kt*64 + 2*cpair;
      const float* q0 = qb + (size_t)c*32768 + n0 + nq;
      const float* q1 = q0 + 32768;
      #pragma unroll
      for (int i=0;i<4;++i){
        float a  = q0[32*i];
        float bb = q1[32*i];
        uint32 dw = (uint32)f2bf(a) | ((uint32)f2bf(bb)<<16);
        *(uint32*)(Bs + (nq+32*i)*72 + 2*cpair) = dw;
      }
    }
    __syncthreads();
    #pragma unroll
    for (int ks=0; ks<2; ++ks){
      bf16x8 af[4], bfr[4];
      #pragma unroll
      for (int i=0;i<4;++i) af[i]  = *(const bf16x8*)(As + (wco + i*16 + m16)*72 + ks*32 + quad*8);
      #pragma unroll
      for (int j=0;j<4;++j) bfr[j] = *(const bf16x8*)(Bs + (wn + j*16 + m16)*72 + ks*32 + quad*8);
      #pragma unroll
      for (int i=0;i<4;++i){
        #pragma unroll
        for (int j=0;j<4;++j)
          acc[i][j] = __builtin_amdgcn_mfma_f32_16x16x32_bf16(af[i], bfr[j], acc[i][j], 0, 0, 0);
      }
    }
    __syncthreads();
  }
  // epilogue: acc -> Cs (bf16, [co][n]), then coalesced read-back + fp32 q residual + Kb
  #pragma unroll
  for (int i=0;i<4;++i){
    #pragma unroll
    for (int r=0;r<4;++r){
      int row = wco + i*16 + quad*4 + r;
      #pragma unroll
      for (int j=0;j<4;++j)
        Cs[row*136 + wn + j*16 + m16] = f2bf(acc[i][j][r]);
    }
  }
  __syncthreads();
  {
    int co = co0 + r2;
    float kbv = ws[OFF_KB + b*256 + co];
    u16* zp = (u16*)(ws + OFF_Z) + (size_t)b*8388608 + (size_t)co*32768 + n0 + seg*64;
    const float* qr = qb + (size_t)co*32768 + n0 + seg*64;
    #pragma unroll
    for (int ch=0; ch<8; ++ch){
      uint4 cv = *(const uint4*)(Cs + r2*136 + seg*64 + ch*8);
      float4 qa = *(const float4*)(qr + ch*8);
      float4 qc = *(const float4*)(qr + ch*8 + 4);
      float z0 = qa.x + bf2f((u16)(cv.x&0xffff)) + kbv;
      float z1 = qa.y + bf2f((u16)(cv.x>>16))    + kbv;
      float z2 = qa.z + bf2f((u16)(cv.y&0xffff)) + kbv;
      float z3 = qa.w + bf2f((u16)(cv.y>>16))    + kbv;
      float z4 = qc.x + bf2f((u16)(cv.z&0xffff)) + kbv;
      float z5 = qc.y + bf2f((u16)(cv.z>>16))    + kbv;
      float z6 = qc.z + bf2f((u16)(cv.w&0xffff)) + kbv;
      float z7 = qc.w + bf2f((u16)(cv.w>>16))    + kbv;
      uint4 u;
      u.x = (uint32)f2bf(z0) | ((uint32)f2bf(z1)<<16);
      u.y = (uint32)f2bf(z2) | ((uint32)f2bf(z3)<<16);
      u.z = (uint32)f2bf(z4) | ((uint32)f2bf(z5)<<16);
      u.w = (uint32)f2bf(z6) | ((uint32)f2bf(z7)<<16);
      *(uint4*)(zp + ch*8) = u;
    }
  }
}

// ---------------- 6. dg conv: 3x3x3, 256 -> 3, pad 1; register-direct, no im2col ----------------
// thread = (wt, hy, dx): one 16-wide w-row at (d0+dx, h0+hy), 3 out channels.
// 9 halo rows per channel read straight from global (L1/L2 reuse), packed-word cndmask for borders.
__global__ __launch_bounds__(256) void k_dg(const float* __restrict__ dgw, float* __restrict__ ws, int usePart){
  int tile = blockIdx.x;        // 0..7
  int split = blockIdx.y;       // 0..31 (8 ci each)
  int b = blockIdx.z;
  int d0 = (tile>>1)*8, h0=(tile&1)*16;
  int tid = threadIdx.x;
  int wt = tid&1, hy=(tid>>1)&15, dx=tid>>5;
  int d = d0+dx, h = h0+hy, w0 = wt*16;
  int cbeg = split*8;
  __shared__ float wss[8][27][4];     // [ci][tap][{o0,o1,o2,pad}]
  for (int i=tid;i<864;i+=256){
    int ci = i/108; int r = i - ci*108; int tap = r>>2; int o = r&3;
    wss[ci][tap][o] = (o<3)? dgw[o*6912 + (cbeg+ci)*27 + tap] : 0.f;
  }
  __syncthreads();
  const u16* zp = (const u16*)(ws+OFF_Z) + (size_t)b*8388608;
  float acc[3][16];
  #pragma unroll
  for (int o=0;o<3;++o){
    #pragma unroll
    for (int j=0;j<16;++j) acc[o][j]=0.f;
  }
  for (int ci=0; ci<8; ++ci){
    const u16* zc = zp + (size_t)(cbeg+ci)*32768;
    #pragma unroll
    for (int kd=0;kd<3;++kd){
      int gd = d+kd-1;
      #pragma unroll
      for (int kh=0;kh<3;++kh){
        int gh = h+kh-1;
        bool rv = (gd>=0) & (gd<32) & (gh>=0) & (gh<32);
        const u16* rowp = zc + gd*1024 + gh*32 + w0;
        // loads stay inside ws even when gd/gh step out by one plane/row
        uint4 u0 = *(const uint4*)(rowp);
        uint4 u1 = *(const uint4*)(rowp+8);
        u16 le = (wt==0)? (u16)0 : rowp[-1];
        u16 ri = (wt==1)? (u16)0 : rowp[16];
        if (!rv){ u0 = make_uint4(0,0,0,0); u1 = make_uint4(0,0,0,0); le = 0; ri = 0; }
        float r[18];
        r[0]  = bf2f(le);
        r[1]  = bf2f((u16)(u0.x&0xffff)); r[2]  = bf2f((u16)(u0.x>>16));
        r[3]  = bf2f((u16)(u0.y&0xffff)); r[4]  = bf2f((u16)(u0.y>>16));
        r[5]  = bf2f((u16)(u0.z&0xffff)); r[6]  = bf2f((u16)(u0.z>>16));
        r[7]  = bf2f((u16)(u0.w&0xffff)); r[8]  = bf2f((u16)(u0.w>>16));
        r[9]  = bf2f((u16)(u1.x&0xffff)); r[10] = bf2f((u16)(u1.x>>16));
        r[11] = bf2f((u16)(u1.y&0xffff)); r[12] = bf2f((u16)(u1.y>>16));
        r[13] = bf2f((u16)(u1.z&0xffff)); r[14] = bf2f((u16)(u1.z>>16));
        r[15] = bf2f((u16)(u1.w&0xffff)); r[16] = bf2f((u16)(u1.w>>16));
        r[17] = bf2f(ri);
        #pragma unroll
        for (int kw=0;kw<3;++kw){
          float4 wv = *(const float4*)&wss[ci][kd*9+kh*3+kw][0];
          #pragma unroll
          for (int j=0;j<16;++j){
            acc[0][j]=fmaf(r[j+kw],wv.x,acc[0][j]);
            acc[1][j]=fmaf(r[j+kw],wv.y,acc[1][j]);
            acc[2][j]=fmaf(r[j+kw],wv.z,acc[2][j]);
          }
        }
      }
    }
  }
  if (usePart){
    float* op = ws + OFF_DGP + (size_t)split*196608 + (size_t)b*98304;
    #pragma unroll
    for (int o=0;o<3;++o){
      int base = o*32768 + d*1024 + h*32 + w0;
      *(float4*)&op[base+0]  = make_float4(acc[o][0],acc[o][1],acc[o][2],acc[o][3]);
      *(float4*)&op[base+4]  = make_float4(acc[o][4],acc[o][5],acc[o][6],acc[o][7]);
      *(float4*)&op[base+8]  = make_float4(acc[o][8],acc[o][9],acc[o][10],acc[o][11]);
      *(float4*)&op[base+12] = make_float4(acc[o][12],acc[o][13],acc[o][14],acc[o][15]);
    }
  } else {
    float* op = ws + OFF_DG + (size_t)b*98304;
    #pragma unroll
    for (int o=0;o<3;++o){
      #pragma unroll
      for (int j=0;j<16;++j)
        atomicAdd(&op[o*32768 + d*1024 + h*32 + w0 + j], acc[o][j]);
    }
  }
}

__global__ void k_dgred(float* __restrict__ ws){
  int i = blockIdx.x*256 + threadIdx.x; // < 196608
  float s = 0.f;
  const float* p = ws + OFF_DGP + i;
  #pragma unroll 8
  for (int c=0;c<32;++c) s += p[(size_t)c*196608];
  ws[OFF_DG + i] = s;
}

// ---------------- 7. upsample x2 nearest + 3x3x3 conv (3->3), pad 1 ----------------
__global__ __launch_bounds__(256) void k_up(const float* __restrict__ dgb, const float* __restrict__ nlw,
                                            const float* __restrict__ nlb, const float* __restrict__ ws,
                                            float* __restrict__ out){
  int b = blockIdx.y; int tileIdx = blockIdx.x;
  int zt0 = (tileIdx&7)*8, yt0 = ((tileIdx>>3)&7)*8, xt0 = (tileIdx>>6)*4;
  int sx0 = (xt0>>1)-1, sy0 = (yt0>>1)-1, sz0 = (zt0>>1)-1;
  __shared__ float ds[3][4][6][6];
  __shared__ float wl[243];
  const float* dgp = ws + OFF_DG + (size_t)b*98304;
  for (int i=threadIdx.x; i<432; i+=256){
    int ch = i/144; int r = i-ch*144; int sx=r/36; int rr=r-sx*36; int sy=rr/6; int sz=rr-sy*6;
    int gx = sx0+sx, gy = sy0+sy, gz = sz0+sz;
    float v=0.f;
    if (gx>=0&&gx<32&&gy>=0&&gy<32&&gz>=0&&gz<32) v = dgp[ch*32768 + gx*1024 + gy*32 + gz] + dgb[ch];
    ds[ch][sx][sy][sz] = v;
  }
  for (int i=threadIdx.x;i<243;i+=256) wl[i] = nlw[i];
  __syncthreads();
  int zt = threadIdx.x&7, yt=(threadIdx.x>>3)&7, xt=threadIdx.x>>6;
  int x = xt0+xt, y=yt0+yt, zc=zt0+zt;
  float a0=nlb[0], a1=nlb[1], a2=nlb[2];
  #pragma unroll
  for (int i=0;i<3;++i){
    #pragma unroll
    for (int kd=0;kd<3;++kd){
      int sxi = ((x+kd-1)>>1) - sx0;
      #pragma unroll
      for (int kh=0;kh<3;++kh){
        int syi = ((y+kh-1)>>1) - sy0;
        #pragma unroll
        for (int kw=0;kw<3;++kw){
          int szi = ((zc+kw-1)>>1) - sz0;
          float vv = ds[i][sxi][syi][szi];
          int tap = kd*9+kh*3+kw;
          a0 = fmaf(vv, wl[i*27+tap],      a0);
          a1 = fmaf(vv, wl[81+i*27+tap],   a1);
          a2 = fmaf(vv, wl[162+i*27+tap],  a2);
        }
      }
    }
  }
  size_t o0 = (size_t)b*786432 + (size_t)x*4096 + y*64 + zc;
  out[o0] = a0; out[o0+262144] = a1; out[o0+524288] = a2;
}

// ---------------- launch ----------------
extern "C" void kernel_launch(void* const* d_in, const int* in_sizes, int n_in,
                              void* d_out, int out_size, void* d_ws, size_t ws_size,
                              hipStream_t stream){
  const float* q    = (const float*)d_in[0];
  const float* k    = (const float*)d_in[1];
  const float* v    = (const float*)d_in[2];
  const float* gnw  = (const float*)d_in[3];
  const float* gnb  = (const float*)d_in[4];
  const float* outw = (const float*)d_in[5];
  const float* outb = (const float*)d_in[6];
  const float* dgw  = (const float*)d_in[7];
  const float* dgb  = (const float*)d_in[8];
  const float* nlw  = (const float*)d_in[9];
  const float* nlb  = (const float*)d_in[10];
  float* out = (float*)d_out;
  float* ws  = (float*)d_ws;
  int usePart = (ws_size >= (size_t)WS_PART_FLOATS*4) ? 1 : 0;

  (void)hipMemsetAsync(ws, 0, 139264, stream);                       // stats..ctx region
  (void)hipMemsetAsync((void*)(ws + OFF_DG), 0, 196608*4, stream);   // dg final (atomic fallback)

  k_stats   <<<dim3(1536),   dim3(256), 0, stream>>>(q,k,v,ws);
  k_finalize<<<dim3(1),      dim3(512), 0, stream>>>(gnw,gnb,ws);
  k_ctx     <<<dim3(64,8),   dim3(256), 0, stream>>>(k,v,gnw,gnb,ws,usePart);
  if (usePart) k_ctxred<<<dim3(130), dim3(256), 0, stream>>>(ws);
  k_weff    <<<dim3(256,2),  dim3(256), 0, stream>>>(outw,outb,gnw,gnb,ws);
  k_z       <<<dim3(256,2,2),dim3(256), 36864, stream>>>(q,ws);
  k_dg      <<<dim3(8,32,2), dim3(256), 0, stream>>>(dgw,ws,usePart);
  if (usePart) k_dgred<<<dim3(768), dim3(256), 0, stream>>>(ws);
  k_up      <<<dim3(1024,2), dim3(256), 0, stream>>>(dgb,nlw,nlb,ws,out);
}